// Round 1
// baseline (1374.272 us; speedup 1.0000x reference)
//
#include <hip/hip_runtime.h>
#include <math.h>

#define B_   128
#define N_   1024
#define D_   256
#define G_   64
#define GSZ_ 3
#define RD_  16
#define KD_  64
#define PD_  64
#define NF_  64
#define Q_   (G_*GSZ_)   // 192

// ---------------------------------------------------------------------------
// Kernel P: symmetrized, transposed filters.
// filt_symT[uvr][f] = (1/6) * sum_{sigma in S3} filters[f, sigma(u), sigma(v), r]
// (permutation-mean commuted into the filters; S3 is a group so the set of
//  inverse perms == the set of perms)
// ---------------------------------------------------------------------------
__global__ void filt_sym_kernel(const float* __restrict__ filters,
                                float* __restrict__ fsT) {
    int flat = blockIdx.x * 256 + threadIdx.x;
    if (flat >= NF_ * 144) return;
    int f = flat / 144, uvr = flat % 144;
    int u = uvr / 48, v = (uvr / 16) % 3, r = uvr % 16;
    const int perm[6][3] = {{0,1,2},{0,2,1},{1,0,2},{1,2,0},{2,0,1},{2,1,0}};
    float s = 0.f;
#pragma unroll
    for (int p = 0; p < 6; ++p)
        s += filters[f*144 + perm[p][u]*48 + perm[p][v]*16 + r];
    fsT[uvr * NF_ + f] = s * (1.0f / 6.0f);
}

// ---------------------------------------------------------------------------
// Kernel A: kT[b][kd][n] = sum_d x[b][n][d]*Wk_map[d][kd] + PE(n,kd)
// Stored transposed so stage-2 reads are coalesced over n.
// ---------------------------------------------------------------------------
__global__ __launch_bounds__(256)
void k_proj_kernel(const float* __restrict__ x,
                   const float* __restrict__ Wk_map,
                   float* __restrict__ kT) {
    __shared__ float xs[256][33];   // +1 pad: (t + dl) % 32 -> conflict-free
    __shared__ float wsm[32][64];
    int b  = blockIdx.y;
    int n0 = blockIdx.x * 256;
    int t  = threadIdx.x;

    float acc[64];
#pragma unroll
    for (int i = 0; i < 64; ++i) acc[i] = 0.f;

    for (int dc = 0; dc < 8; ++dc) {        // 8 chunks of 32 d's
#pragma unroll
        for (int i = 0; i < 32; ++i) {
            int flat = i * 256 + t;
            int nl = flat >> 5, dl = flat & 31;
            xs[nl][dl] = x[((size_t)b * N_ + n0 + nl) * D_ + dc * 32 + dl];
        }
#pragma unroll
        for (int i = 0; i < 8; ++i) {
            int flat = i * 256 + t;
            int dl = flat >> 6, kd = flat & 63;
            wsm[dl][kd] = Wk_map[(dc * 32 + dl) * KD_ + kd];
        }
        __syncthreads();
#pragma unroll 4
        for (int dl = 0; dl < 32; ++dl) {
            float xv = xs[t][dl];
#pragma unroll
            for (int kd = 0; kd < 64; ++kd)
                acc[kd] += xv * wsm[dl][kd];   // wsm: broadcast read
        }
        __syncthreads();
    }

    int n = n0 + t;
#pragma unroll 8
    for (int kd = 0; kd < 64; ++kd) {
        float ex    = -2.0f * (float)(kd >> 1) / (float)KD_ * logf(10000.0f);
        float angle = (float)n * expf(ex);
        float pe    = (kd & 1) ? cosf(angle) : sinf(angle);
        kT[((size_t)b * KD_ + kd) * N_ + n] = acc[kd] + pe;   // coalesced over n
    }
}

// ---------------------------------------------------------------------------
// Kernel B: per (b, tile of 8 queries): logits -> softmax -> gobj = scores @ x
// scores kept unnormalized in LDS; 1/sum folded into the epilogue.
// ---------------------------------------------------------------------------
__global__ __launch_bounds__(256)
void attn_kernel(const float* __restrict__ x,
                 const float* __restrict__ query_emb,
                 const float* __restrict__ kT,
                 float* __restrict__ gobj) {
    __shared__ float qes[8][64];
    __shared__ float sc[8][1024];
    __shared__ float red[4];
    __shared__ float inv_sum[8];

    int b  = blockIdx.y;
    int q0 = blockIdx.x * 8;
    int t  = threadIdx.x;
    int lane = t & 63, wv = t >> 6;

#pragma unroll
    for (int i = 0; i < 2; ++i) {
        int flat = i * 256 + t;
        qes[flat >> 6][flat & 63] = query_emb[(q0 + (flat >> 6)) * KD_ + (flat & 63)];
    }
    __syncthreads();

    // phase 1: logits (kT read once per block; 8 FMA per 4B load)
    for (int c = 0; c < 4; ++c) {
        int n = c * 256 + t;
        float acc[8];
#pragma unroll
        for (int q = 0; q < 8; ++q) acc[q] = 0.f;
        const float* kp = kT + (size_t)b * KD_ * N_ + n;
#pragma unroll 8
        for (int kd = 0; kd < 64; ++kd) {
            float kv = kp[(size_t)kd * N_];        // coalesced over n
#pragma unroll
            for (int q = 0; q < 8; ++q) acc[q] += qes[q][kd] * kv;
        }
#pragma unroll
        for (int q = 0; q < 8; ++q) sc[q][n] = 0.125f * acc[q];  // beta = KD^-0.5
    }
    __syncthreads();

    // phase 2: softmax stats per q
    for (int q = 0; q < 8; ++q) {
        float m = -1e30f;
#pragma unroll
        for (int c = 0; c < 4; ++c) m = fmaxf(m, sc[q][c * 256 + t]);
#pragma unroll
        for (int off = 32; off > 0; off >>= 1) m = fmaxf(m, __shfl_xor(m, off, 64));
        if (lane == 0) red[wv] = m;
        __syncthreads();
        m = fmaxf(fmaxf(red[0], red[1]), fmaxf(red[2], red[3]));
        float s = 0.f;
#pragma unroll
        for (int c = 0; c < 4; ++c) {
            float e = __expf(sc[q][c * 256 + t] - m);
            sc[q][c * 256 + t] = e;
            s += e;
        }
#pragma unroll
        for (int off = 32; off > 0; off >>= 1) s += __shfl_xor(s, off, 64);
        __syncthreads();             // everyone done reading red (max phase)
        if (lane == 0) red[wv] = s;
        __syncthreads();
        if (t == 0) inv_sum[q] = 1.0f / (red[0] + red[1] + red[2] + red[3]);
        __syncthreads();             // red reused next q; inv_sum visible later
    }

    // phase 3: gobj[b][q0+q][d], thread t == d
    float acc[8];
#pragma unroll
    for (int q = 0; q < 8; ++q) acc[q] = 0.f;
    const float* xp = x + (size_t)b * N_ * D_ + t;
    for (int n = 0; n < N_; ++n) {
        float xv = xp[(size_t)n * D_];             // coalesced over d
#pragma unroll
        for (int q = 0; q < 8; ++q) acc[q] += sc[q][n] * xv;   // broadcast reads
    }
#pragma unroll
    for (int q = 0; q < 8; ++q)
        gobj[((size_t)b * Q_ + q0 + q) * D_ + t] = acc[q] * inv_sum[q];
}

// ---------------------------------------------------------------------------
// Kernel C: per (b,g): zq/zk -> R (shfl-reduce over p) -> out = R . filt_sym
// ---------------------------------------------------------------------------
__global__ __launch_bounds__(256)
void rel_kernel(const float* __restrict__ gobj,
                const float* __restrict__ Wq,
                const float* __restrict__ Wk,
                const float* __restrict__ fsT,
                float* __restrict__ out) {
    __shared__ float gsm[3][256];
    __shared__ float Rsm[144];      // [n][m][r] = n*48 + m*16 + r

    int b = blockIdx.x >> 6, g = blockIdx.x & 63;
    int t = threadIdx.x;
    int lane = t & 63, wv = t >> 6;

#pragma unroll
    for (int n = 0; n < 3; ++n)
        gsm[n][t] = gobj[((size_t)b * Q_ + g * 3 + n) * D_ + t];
    __syncthreads();

    // lane = p (0..63); each wave covers r = wv*4 .. wv*4+3
#pragma unroll
    for (int it = 0; it < 4; ++it) {
        int r = wv * 4 + it;
        float zq0 = 0, zq1 = 0, zq2 = 0, zk0 = 0, zk1 = 0, zk2 = 0;
        const float* wqp = Wq + (size_t)r * D_ * PD_ + lane;
        const float* wkp = Wk + (size_t)r * D_ * PD_ + lane;
#pragma unroll 4
        for (int d = 0; d < 256; ++d) {
            float wq = wqp[d * PD_];     // coalesced over p
            float wk = wkp[d * PD_];
            float g0 = gsm[0][d], g1 = gsm[1][d], g2 = gsm[2][d];  // broadcast
            zq0 += g0 * wq; zq1 += g1 * wq; zq2 += g2 * wq;
            zk0 += g0 * wk; zk1 += g1 * wk; zk2 += g2 * wk;
        }
        float zq[3] = {zq0, zq1, zq2}, zk[3] = {zk0, zk1, zk2};
#pragma unroll
        for (int n = 0; n < 3; ++n)
#pragma unroll
            for (int m = 0; m < 3; ++m) {
                float p = zq[n] * zk[m];
#pragma unroll
                for (int off = 32; off > 0; off >>= 1) p += __shfl_xor(p, off, 64);
                if (lane == 0) Rsm[n * 48 + m * 16 + r] = p;
            }
    }
    __syncthreads();

    if (t < 64) {
        float acc = 0.f;
#pragma unroll 16
        for (int idx = 0; idx < 144; ++idx)
            acc += Rsm[idx] * fsT[idx * NF_ + t];   // coalesced over f
        out[(size_t)blockIdx.x * NF_ + t] = acc;
    }
}

// ---------------------------------------------------------------------------
extern "C" void kernel_launch(void* const* d_in, const int* in_sizes, int n_in,
                              void* d_out, int out_size, void* d_ws, size_t ws_size,
                              hipStream_t stream) {
    const float* x         = (const float*)d_in[0];
    const float* filters   = (const float*)d_in[1];
    const float* query_emb = (const float*)d_in[2];
    const float* Wk_map    = (const float*)d_in[3];
    const float* Wq        = (const float*)d_in[4];
    const float* Wk        = (const float*)d_in[5];
    float* out = (float*)d_out;

    float* kT   = (float*)d_ws;                      // B*KD*N   = 8,388,608 f
    float* gobj = kT + (size_t)B_ * KD_ * N_;        // B*Q*D    = 6,291,456 f
    float* fsT  = gobj + (size_t)B_ * Q_ * D_;       // 144*NF   =     9,216 f
                                                     // total ~58.8 MB of ws

    hipLaunchKernelGGL(filt_sym_kernel, dim3(36), dim3(256), 0, stream,
                       filters, fsT);
    hipLaunchKernelGGL(k_proj_kernel, dim3(4, 128), dim3(256), 0, stream,
                       x, Wk_map, kT);
    hipLaunchKernelGGL(attn_kernel, dim3(24, 128), dim3(256), 0, stream,
                       x, query_emb, kT, gobj);
    hipLaunchKernelGGL(rel_kernel, dim3(8192), dim3(256), 0, stream,
                       gobj, Wq, Wk, fsT, out);
}

// Round 2
// 748.940 us; speedup vs baseline: 1.8350x; 1.8350x over previous
//
#include <hip/hip_runtime.h>
#include <math.h>

#define B_   128
#define N_   1024
#define D_   256
#define G_   64
#define GSZ_ 3
#define RD_  16
#define KD_  64
#define PD_  64
#define NF_  64
#define Q_   (G_*GSZ_)   // 192

typedef __attribute__((ext_vector_type(8))) short bf16x8;   // 8 bf16 = 4 VGPRs
typedef __attribute__((ext_vector_type(4))) float f32x4;
typedef __attribute__((ext_vector_type(4))) short short4_;

__device__ __forceinline__ unsigned short f2bf(float f) {
    unsigned int u = __float_as_uint(f);
    u += 0x7fffu + ((u >> 16) & 1u);       // RNE
    return (unsigned short)(u >> 16);
}

// ---------------------------------------------------------------------------
// coef_kernel: the S3-symmetrized filter has only 2 DOF per (f,r):
//   a[f,r] = (1/3) sum_u  filt[f,u,u,r]     (diagonal orbit)
//   b[f,r] = (1/6) sum_{u!=v} filt[f,u,v,r] (off-diagonal orbit)
// out = sum_r (a-b)*T1 + b*T2.  coef[0..1023]=c1=a-b, coef[1024..2047]=c2=b.
// ---------------------------------------------------------------------------
__global__ void coef_kernel(const float* __restrict__ filters,
                            float* __restrict__ coef) {
    int flat = blockIdx.x * 256 + threadIdx.x;
    if (flat >= NF_ * RD_) return;
    int f = flat >> 4, r = flat & 15;
    const float* F = filters + f * 144 + r;
    float diag = F[0] + F[48 + 16] + F[96 + 32];
    float all = 0.f;
#pragma unroll
    for (int u = 0; u < 3; ++u)
#pragma unroll
        for (int v = 0; v < 3; ++v) all += F[u * 48 + v * 16];
    float a = diag * (1.f / 3.f);
    float b = (all - diag) * (1.f / 6.f);
    coef[f * 16 + r] = a - b;
    coef[1024 + f * 16 + r] = b;
}

// ---------------------------------------------------------------------------
// wb_kernel: Wb[col][d] = bf16 of (col<1024 ? Wq : Wk)[r=colh>>6][d][p=colh&63]
// Column-major (k contiguous) so rel2's B-frag LDS staging is 16B vector loads.
// ---------------------------------------------------------------------------
__global__ void wb_kernel(const float* __restrict__ Wq,
                          const float* __restrict__ Wk,
                          unsigned short* __restrict__ Wb) {
    int flat = blockIdx.x * 256 + threadIdx.x;     // [0, 2048*256)
    int d = flat & 255, col = flat >> 8;
    int ch = col & 1023;
    const float* W = (col >> 10) ? Wk : Wq;
    float v = W[((size_t)(ch >> 6) * 256 + d) * 64 + (ch & 63)];
    Wb[(size_t)col * 256 + d] = f2bf(v);
}

// ---------------------------------------------------------------------------
// Kernel A: kT[b][kd][n] = sum_d x[b][n][d]*Wk_map[d][kd] + PE(n,kd)
// ---------------------------------------------------------------------------
__global__ __launch_bounds__(256)
void k_proj_kernel(const float* __restrict__ x,
                   const float* __restrict__ Wk_map,
                   float* __restrict__ kT) {
    __shared__ float xs[256][33];
    __shared__ float wsm[32][64];
    int b  = blockIdx.y;
    int n0 = blockIdx.x * 256;
    int t  = threadIdx.x;

    float acc[64];
#pragma unroll
    for (int i = 0; i < 64; ++i) acc[i] = 0.f;

    for (int dc = 0; dc < 8; ++dc) {
#pragma unroll
        for (int i = 0; i < 32; ++i) {
            int flat = i * 256 + t;
            int nl = flat >> 5, dl = flat & 31;
            xs[nl][dl] = x[((size_t)b * N_ + n0 + nl) * D_ + dc * 32 + dl];
        }
#pragma unroll
        for (int i = 0; i < 8; ++i) {
            int flat = i * 256 + t;
            int dl = flat >> 6, kd = flat & 63;
            wsm[dl][kd] = Wk_map[(dc * 32 + dl) * KD_ + kd];
        }
        __syncthreads();
#pragma unroll 4
        for (int dl = 0; dl < 32; ++dl) {
            float xv = xs[t][dl];
#pragma unroll
            for (int kd = 0; kd < 64; ++kd)
                acc[kd] += xv * wsm[dl][kd];
        }
        __syncthreads();
    }

    int n = n0 + t;
#pragma unroll 8
    for (int kd = 0; kd < 64; ++kd) {
        float ex    = -2.0f * (float)(kd >> 1) / (float)KD_ * logf(10000.0f);
        float angle = (float)n * expf(ex);
        float pe    = (kd & 1) ? cosf(angle) : sinf(angle);
        kT[((size_t)b * KD_ + kd) * N_ + n] = acc[kd] + pe;
    }
}

// ---------------------------------------------------------------------------
// Kernel B: per (b, tile of 8 queries): logits -> softmax -> gobj = scores @ x
// ---------------------------------------------------------------------------
__global__ __launch_bounds__(256)
void attn_kernel(const float* __restrict__ x,
                 const float* __restrict__ query_emb,
                 const float* __restrict__ kT,
                 float* __restrict__ gobj) {
    __shared__ float qes[8][64];
    __shared__ float sc[8][1024];
    __shared__ float red[4];
    __shared__ float inv_sum[8];

    int b  = blockIdx.y;
    int q0 = blockIdx.x * 8;
    int t  = threadIdx.x;
    int lane = t & 63, wv = t >> 6;

#pragma unroll
    for (int i = 0; i < 2; ++i) {
        int flat = i * 256 + t;
        qes[flat >> 6][flat & 63] = query_emb[(q0 + (flat >> 6)) * KD_ + (flat & 63)];
    }
    __syncthreads();

    for (int c = 0; c < 4; ++c) {
        int n = c * 256 + t;
        float acc[8];
#pragma unroll
        for (int q = 0; q < 8; ++q) acc[q] = 0.f;
        const float* kp = kT + (size_t)b * KD_ * N_ + n;
#pragma unroll 8
        for (int kd = 0; kd < 64; ++kd) {
            float kv = kp[(size_t)kd * N_];
#pragma unroll
            for (int q = 0; q < 8; ++q) acc[q] += qes[q][kd] * kv;
        }
#pragma unroll
        for (int q = 0; q < 8; ++q) sc[q][n] = 0.125f * acc[q];
    }
    __syncthreads();

    for (int q = 0; q < 8; ++q) {
        float m = -1e30f;
#pragma unroll
        for (int c = 0; c < 4; ++c) m = fmaxf(m, sc[q][c * 256 + t]);
#pragma unroll
        for (int off = 32; off > 0; off >>= 1) m = fmaxf(m, __shfl_xor(m, off, 64));
        if (lane == 0) red[wv] = m;
        __syncthreads();
        m = fmaxf(fmaxf(red[0], red[1]), fmaxf(red[2], red[3]));
        float s = 0.f;
#pragma unroll
        for (int c = 0; c < 4; ++c) {
            float e = __expf(sc[q][c * 256 + t] - m);
            sc[q][c * 256 + t] = e;
            s += e;
        }
#pragma unroll
        for (int off = 32; off > 0; off >>= 1) s += __shfl_xor(s, off, 64);
        __syncthreads();
        if (lane == 0) red[wv] = s;
        __syncthreads();
        if (t == 0) inv_sum[q] = 1.0f / (red[0] + red[1] + red[2] + red[3]);
        __syncthreads();
    }

    float acc[8];
#pragma unroll
    for (int q = 0; q < 8; ++q) acc[q] = 0.f;
    const float* xp = x + (size_t)b * N_ * D_ + t;
    for (int n = 0; n < N_; ++n) {
        float xv = xp[(size_t)n * D_];
#pragma unroll
        for (int q = 0; q < 8; ++q) acc[q] += sc[q][n] * xv;
    }
#pragma unroll
    for (int q = 0; q < 8; ++q)
        gobj[((size_t)b * Q_ + q0 + q) * D_ + t] = acc[q] * inv_sum[q];
}

// ---------------------------------------------------------------------------
// rel2: per block, 16 (b,g) units. A = gobj rows padded 3->4 (n=3 zeroed),
// 64x256 bf16 in LDS. For each r: stage Wq[r] tile (64 cols x 256 k bf16),
// MFMA Zq (4 M-tiles x 4 wave-strips), same for Wk[r], then T1/T2 straight
// from C-fragments (lane's 4 regs = one bg's 4 n-rows), shfl-reduce over the
// 16 p-columns per wave, partials in LDS, final 32-term dot with c1/c2.
// ---------------------------------------------------------------------------
#define APITCH 264   // 256 + 8 bf16 pad: row stride 132 dwords -> 2-way banks (free)

__global__ __launch_bounds__(256, 2)
void rel2_kernel(const float* __restrict__ gobj,
                 const unsigned short* __restrict__ Wb,
                 const float* __restrict__ coef,
                 float* __restrict__ out) {
    __shared__ unsigned short As[64 * APITCH];
    __shared__ unsigned short Ws[64 * APITCH];
    __shared__ float Tp[4 * 16 * 2 * 16];   // [wave][bg][T1|T2][r]

    int t = threadIdx.x;
    int w = t >> 6, lane = t & 63;
    int quad = lane >> 4, lcol = lane & 15;
    int bg0 = blockIdx.x * 16;

    // ---- zero the n=3 padding rows (rows 3,7,...,63), k-cols 0..255
    for (int i = 0; i < 8; ++i) {
        int idx = i * 256 + t;               // [0, 2048) dwords
        int r3 = idx >> 7, c3 = idx & 127;   // 16 rows x 128 dwords
        ((unsigned int*)As)[(r3 * 4 + 3) * (APITCH / 2) + c3] = 0u;
    }
    // ---- stage A: 48 gobj rows -> bf16, row = (j/3)*4 + j%3
#pragma unroll
    for (int it = 0; it < 12; ++it) {
        int flat4 = it * 256 + t;            // [0, 3072): 48 rows x 64 float4
        int j = flat4 >> 6, c4 = flat4 & 63;
        const float* src = gobj + ((size_t)(bg0 * 3 + j)) * 256 + c4 * 4;
        float4 v = *(const float4*)src;
        short4_ h;
        h.x = (short)f2bf(v.x); h.y = (short)f2bf(v.y);
        h.z = (short)f2bf(v.z); h.w = (short)f2bf(v.w);
        *(short4_*)(&As[((j / 3) * 4 + (j % 3)) * APITCH + c4 * 4]) = h;
    }

    f32x4 zq[4], zk[4];
    for (int r = 0; r < 16; ++r) {
#pragma unroll
        for (int half = 0; half < 2; ++half) {
            __syncthreads();                  // As ready / Ws free for reuse
            const unsigned short* src = Wb + (size_t)(r + half * 16) * 64 * 256;
#pragma unroll
            for (int it = 0; it < 8; ++it) {
                int flat = it * 256 + t;      // [0, 2048): 64 cols x 32 chunks
                int col = flat >> 5, ch = flat & 31;
                uint4 v = *(const uint4*)(src + col * 256 + ch * 8);
                *(uint4*)(&Ws[col * APITCH + ch * 8]) = v;
            }
            __syncthreads();

            f32x4* z = half ? zk : zq;
#pragma unroll
            for (int i = 0; i < 4; ++i) z[i] = (f32x4)(0.f);
#pragma unroll
            for (int kk = 0; kk < 8; ++kk) {
                bf16x8 bfrag = *(const bf16x8*)(&Ws[(w * 16 + lcol) * APITCH + kk * 32 + quad * 8]);
#pragma unroll
                for (int mt = 0; mt < 4; ++mt) {
                    bf16x8 afrag = *(const bf16x8*)(&As[(mt * 16 + lcol) * APITCH + kk * 32 + quad * 8]);
                    z[mt] = __builtin_amdgcn_mfma_f32_16x16x32_bf16(afrag, bfrag, z[mt], 0, 0, 0);
                }
            }
        }
        // ---- T1/T2 partials: lane holds Z[bg = mt*4+quad][n = reg][p = w*16+lcol]
#pragma unroll
        for (int mt = 0; mt < 4; ++mt) {
            float t1 = zq[mt].x * zk[mt].x + zq[mt].y * zk[mt].y +
                       zq[mt].z * zk[mt].z + zq[mt].w * zk[mt].w;
            float sq = zq[mt].x + zq[mt].y + zq[mt].z + zq[mt].w;
            float sk = zk[mt].x + zk[mt].y + zk[mt].z + zk[mt].w;
            float t2 = sq * sk;
#pragma unroll
            for (int off = 1; off < 16; off <<= 1) {
                t1 += __shfl_xor(t1, off, 64);
                t2 += __shfl_xor(t2, off, 64);
            }
            if (lcol == 0) {
                int bgl = mt * 4 + quad;
                Tp[((w * 16 + bgl) * 2 + 0) * 16 + r] = t1;
                Tp[((w * 16 + bgl) * 2 + 1) * 16 + r] = t2;
            }
        }
    }
    __syncthreads();

    // ---- out[bg][f] = sum_r c1[f,r]*T1 + c2[f,r]*T2
    int f = t & 63;
#pragma unroll
    for (int i = 0; i < 4; ++i) {
        int bgl = w * 4 + i;
        float acc = 0.f;
#pragma unroll
        for (int r = 0; r < 16; ++r) {
            float T1 = Tp[((0 * 16 + bgl) * 2 + 0) * 16 + r] + Tp[((1 * 16 + bgl) * 2 + 0) * 16 + r] +
                       Tp[((2 * 16 + bgl) * 2 + 0) * 16 + r] + Tp[((3 * 16 + bgl) * 2 + 0) * 16 + r];
            float T2 = Tp[((0 * 16 + bgl) * 2 + 1) * 16 + r] + Tp[((1 * 16 + bgl) * 2 + 1) * 16 + r] +
                       Tp[((2 * 16 + bgl) * 2 + 1) * 16 + r] + Tp[((3 * 16 + bgl) * 2 + 1) * 16 + r];
            acc += coef[f * 16 + r] * T1 + coef[1024 + f * 16 + r] * T2;
        }
        out[(size_t)(bg0 + bgl) * NF_ + f] = acc;
    }
}

// ---------------------------------------------------------------------------
extern "C" void kernel_launch(void* const* d_in, const int* in_sizes, int n_in,
                              void* d_out, int out_size, void* d_ws, size_t ws_size,
                              hipStream_t stream) {
    const float* x         = (const float*)d_in[0];
    const float* filters   = (const float*)d_in[1];
    const float* query_emb = (const float*)d_in[2];
    const float* Wk_map    = (const float*)d_in[3];
    const float* Wq        = (const float*)d_in[4];
    const float* Wk        = (const float*)d_in[5];
    float* out = (float*)d_out;

    float* kT   = (float*)d_ws;                      // B*KD*N floats (33.5 MB)
    float* gobj = kT + (size_t)B_ * KD_ * N_;        // B*Q*D floats (25.2 MB)
    // After attn_kernel finishes, kT is dead — reuse its space for Wb + coef.
    unsigned short* Wb = (unsigned short*)d_ws;          // 2048*256 bf16 (1 MB)
    float* coef = (float*)((char*)d_ws + (1 << 20));     // 2048 floats

    hipLaunchKernelGGL(k_proj_kernel, dim3(4, 128), dim3(256), 0, stream,
                       x, Wk_map, kT);
    hipLaunchKernelGGL(attn_kernel, dim3(24, 128), dim3(256), 0, stream,
                       x, query_emb, kT, gobj);
    hipLaunchKernelGGL(coef_kernel, dim3(4), dim3(256), 0, stream,
                       filters, coef);
    hipLaunchKernelGGL(wb_kernel, dim3(2048), dim3(256), 0, stream,
                       Wq, Wk, Wb);
    hipLaunchKernelGGL(rel2_kernel, dim3(512), dim3(256), 0, stream,
                       gobj, Wb, coef, out);
}